// Round 3
// baseline (95.947 us; speedup 1.0000x reference)
//
#include <hip/hip_runtime.h>
#include <math.h>

#define NN 4096
#define FF 128
#define DD 64
#define HH 4
#define NC 256  // HH*DD output columns

typedef __bf16 bf16x8 __attribute__((ext_vector_type(8)));
typedef float  f32x4  __attribute__((ext_vector_type(4)));

// ---------------------------------------------------------------------------
// Kernel 0: adjacency int32 -> bitmask. adjw[n*128 + w] bit b = (adj[n][w*32+b])
// ---------------------------------------------------------------------------
__global__ __launch_bounds__(256) void adjbits_kernel(
    const int* __restrict__ adj, unsigned int* __restrict__ adjw)
{
    const int row  = blockIdx.x;
    const int wv   = threadIdx.x >> 6;
    const int lane = threadIdx.x & 63;
    for (int c = wv; c < 64; c += 4) {
        int a = adj[(size_t)row * NN + c * 64 + lane];
        unsigned long long m = __ballot(a != 0);
        if (lane == 0) {
            adjw[row * 128 + c * 2]     = (unsigned int)m;
            adjw[row * 128 + c * 2 + 1] = (unsigned int)(m >> 32);
        }
    }
}

// ---------------------------------------------------------------------------
// Kernel 1: h = features @ W[h]; emit Ht (bf16 [h][d][m], coalesced via LDS
// transpose) and per-node exp tables Es=exp(a_self), Fs=exp(0.2 a_self),
// En=exp(a_neigh), Fn=exp(0.2 a_neigh)  (fp32, [h][n]).
// ---------------------------------------------------------------------------
__global__ __launch_bounds__(256) void prep_kernel(
    const float* __restrict__ feats, const float* __restrict__ W,
    const float* __restrict__ ak, __bf16* __restrict__ Ht,
    float* __restrict__ Es, float* __restrict__ Fs,
    float* __restrict__ En, float* __restrict__ Fn)
{
    __shared__ float Wt[64 * 132];   // W[h] transposed [d][f], padded
    __shared__ float ft[32 * 128];   // features tile [r][f]
    __shared__ float hlds[32 * 65];  // h tile [r][d], padded for transpose
    const int t  = threadIdx.x;
    const int h  = blockIdx.y;
    const int n0 = blockIdx.x * 32;

    {
        const float* Wh = W + h * (FF * DD);
        #pragma unroll
        for (int j = 0; j < 8; ++j) {
            int idx = j * 256 + t;
            int f   = idx >> 4;
            int d4  = idx & 15;
            float4 v = ((const float4*)Wh)[idx];
            Wt[(d4 * 4 + 0) * 132 + f] = v.x;
            Wt[(d4 * 4 + 1) * 132 + f] = v.y;
            Wt[(d4 * 4 + 2) * 132 + f] = v.z;
            Wt[(d4 * 4 + 3) * 132 + f] = v.w;
        }
        #pragma unroll
        for (int j = 0; j < 4; ++j) {
            int idx = j * 256 + t;
            int r = idx >> 5, f4 = idx & 31;
            ((float4*)ft)[r * 32 + f4] = ((const float4*)feats)[(size_t)(n0 + r) * 32 + f4];
        }
    }
    __syncthreads();

    const int d   = t & 63;
    const int wid = t >> 6;
    float acc[8];
    #pragma unroll
    for (int j = 0; j < 8; ++j) acc[j] = 0.f;

    for (int f4 = 0; f4 < 32; ++f4) {
        const float4 w4 = *(const float4*)&Wt[d * 132 + f4 * 4];
        #pragma unroll
        for (int j = 0; j < 8; ++j) {
            const int r = wid + 4 * j;
            const float4 fv = *(const float4*)&ft[r * 128 + f4 * 4];
            acc[j] += fv.x * w4.x + fv.y * w4.y + fv.z * w4.z + fv.w * w4.w;
        }
    }

    const float aks = ak[h * 128 + d];
    const float akn = ak[h * 128 + 64 + d];
    #pragma unroll
    for (int j = 0; j < 8; ++j) {
        const int r = wid + 4 * j;
        const float hv = acc[j];
        hlds[r * 65 + d] = hv;
        float v1 = hv * aks;
        float v2 = hv * akn;
        #pragma unroll
        for (int m = 32; m >= 1; m >>= 1) {
            v1 += __shfl_xor(v1, m, 64);
            v2 += __shfl_xor(v2, m, 64);
        }
        if (d == 0) {
            Es[h * NN + n0 + r] = __expf(v1);
            Fs[h * NN + n0 + r] = __expf(0.2f * v1);
            En[h * NN + n0 + r] = __expf(v2);
            Fn[h * NN + n0 + r] = __expf(0.2f * v2);
        }
    }
    __syncthreads();

    // coalesced transposed store: thread t -> (d2 = t/4, 8 m-values)
    const int d2 = t >> 2;
    const int mq = (t & 3) * 8;
    bf16x8 v;
    #pragma unroll
    for (int i = 0; i < 8; ++i) v[i] = (__bf16)hlds[(mq + i) * 65 + d2];
    *(bf16x8*)(Ht + (size_t)(h * 64 + d2) * NN + n0 + mq) = v;
}

// ---------------------------------------------------------------------------
// Kernel 2: MFMA attention. 1 wave per block; grid (128 row-tiles, 4 heads,
// nsplit m-splits). Factorized exp: P = max(Es*En, Fs*Fn) masked by adj bit.
// Explicit software pipeline: prefetch next chunk's En/Fn/mask registers.
// ---------------------------------------------------------------------------
struct PrefT { float4 en0, en1, fn0, fn1; unsigned int m0, m1; };

__device__ __forceinline__ void load_pref(
    PrefT& p, const float* __restrict__ EnB, const float* __restrict__ FnB,
    const unsigned int* __restrict__ adjw, int row0, int row1, int m0, int kg)
{
    const int mb = m0 + kg * 8;
    p.en0 = *(const float4*)(EnB + mb);
    p.en1 = *(const float4*)(EnB + mb + 4);
    p.fn0 = *(const float4*)(FnB + mb);
    p.fn1 = *(const float4*)(FnB + mb + 4);
    p.m0  = adjw[row0 * 128 + (m0 >> 5)];
    p.m1  = adjw[row1 * 128 + (m0 >> 5)];
}

__global__ __launch_bounds__(64, 4) void attn_kernel(
    const unsigned int* __restrict__ adjw, const __bf16* __restrict__ Ht,
    const float* __restrict__ Es, const float* __restrict__ Fs,
    const float* __restrict__ En, const float* __restrict__ Fn,
    float* __restrict__ pacc, float* __restrict__ pden, int ksplit)
{
    const int l  = threadIdx.x;
    const int lr = l & 15;
    const int kg = l >> 4;
    const int h  = blockIdx.y;
    const int n0 = blockIdx.x * 32;
    const int s  = blockIdx.z;

    const float es0 = Es[h * NN + n0 + lr];
    const float fs0 = Fs[h * NN + n0 + lr];
    const float es1 = Es[h * NN + n0 + 16 + lr];
    const float fs1 = Fs[h * NN + n0 + 16 + lr];
    const float* __restrict__ EnB = En + h * NN;
    const float* __restrict__ FnB = Fn + h * NN;
    const __bf16* __restrict__ htb = Ht + (size_t)(h * 64) * NN;
    const int row0 = n0 + lr, row1 = n0 + 16 + lr;

    f32x4 acc[2][4] = {};
    f32x4 dacc[2]   = {};
    bf16x8 ones;
    #pragma unroll
    for (int j = 0; j < 8; ++j) ones[j] = (__bf16)1.0f;

    const int nchunk = ksplit >> 5;
    const int mstart = s * ksplit;

    PrefT cur, nxt;
    load_pref(cur, EnB, FnB, adjw, row0, row1, mstart, kg);
    nxt = cur;

    for (int c = 0; c < nchunk; ++c) {
        const int m0 = mstart + c * 32;
        const int mb = m0 + kg * 8;

        // B-frags for current chunk (L2-resident Ht)
        bf16x8 B[4];
        #pragma unroll
        for (int cb = 0; cb < 4; ++cb)
            B[cb] = *(const bf16x8*)(htb + (size_t)(cb * 16 + lr) * NN + mb);

        // prefetch next chunk
        if (c + 1 < nchunk)
            load_pref(nxt, EnB, FnB, adjw, row0, row1, m0 + 32, kg);

        // A-frags: P = mask ? max(Es*En, Fs*Fn) : 0
        const float env[8] = {cur.en0.x, cur.en0.y, cur.en0.z, cur.en0.w,
                              cur.en1.x, cur.en1.y, cur.en1.z, cur.en1.w};
        const float fnv[8] = {cur.fn0.x, cur.fn0.y, cur.fn0.z, cur.fn0.w,
                              cur.fn1.x, cur.fn1.y, cur.fn1.z, cur.fn1.w};
        const unsigned int b0 = (cur.m0 >> (kg * 8)) & 0xffu;
        const unsigned int b1 = (cur.m1 >> (kg * 8)) & 0xffu;

        bf16x8 a0, a1;
        #pragma unroll
        for (int j = 0; j < 8; ++j) {
            float v0 = fmaxf(es0 * env[j], fs0 * fnv[j]);
            float v1 = fmaxf(es1 * env[j], fs1 * fnv[j]);
            v0 = ((b0 >> j) & 1u) ? v0 : 0.f;
            v1 = ((b1 >> j) & 1u) ? v1 : 0.f;
            a0[j] = (__bf16)v0;
            a1[j] = (__bf16)v1;
        }

        #pragma unroll
        for (int cb = 0; cb < 4; ++cb) {
            acc[0][cb] = __builtin_amdgcn_mfma_f32_16x16x32_bf16(a0, B[cb], acc[0][cb], 0, 0, 0);
            acc[1][cb] = __builtin_amdgcn_mfma_f32_16x16x32_bf16(a1, B[cb], acc[1][cb], 0, 0, 0);
        }
        dacc[0] = __builtin_amdgcn_mfma_f32_16x16x32_bf16(a0, ones, dacc[0], 0, 0, 0);
        dacc[1] = __builtin_amdgcn_mfma_f32_16x16x32_bf16(a1, ones, dacc[1], 0, 0, 0);

        cur = nxt;
    }

    #pragma unroll
    for (int rb = 0; rb < 2; ++rb) {
        #pragma unroll
        for (int r = 0; r < 4; ++r) {
            const int row = n0 + rb * 16 + kg * 4 + r;
            #pragma unroll
            for (int cb = 0; cb < 4; ++cb)
                pacc[((size_t)(s * NN + row)) * NC + h * 64 + cb * 16 + lr] = acc[rb][cb][r];
            if (lr == 0)
                pden[(s * NN + row) * 4 + h] = dacc[rb][r];
        }
    }
}

// ---------------------------------------------------------------------------
// Kernel 3: reduce splits, normalize, ReLU.
// ---------------------------------------------------------------------------
__global__ __launch_bounds__(256) void finalize_kernel(
    const float* __restrict__ pacc, const float* __restrict__ pden,
    float* __restrict__ out, int nsplit)
{
    const int n = blockIdx.x;
    const int c = threadIdx.x;
    float a = 0.f, d = 0.f;
    for (int s = 0; s < nsplit; ++s) {
        a += pacc[((size_t)(s * NN + n)) * NC + c];
        d += pden[(s * NN + n) * 4 + (c >> 6)];
    }
    const float o = (d > 0.f) ? a / d : 0.f;
    out[(size_t)n * NC + c] = o > 0.f ? o : 0.f;
}

// ---------------------------------------------------------------------------
extern "C" void kernel_launch(void* const* d_in, const int* in_sizes, int n_in,
                              void* d_out, int out_size, void* d_ws, size_t ws_size,
                              hipStream_t stream)
{
    const int*   adj   = (const int*)d_in[0];
    const float* feats = (const float*)d_in[1];
    const float* W     = (const float*)d_in[2];
    const float* ak    = (const float*)d_in[3];
    float*       out   = (float*)d_out;

    char* ws = (char*)d_ws;
    unsigned int* adjw = (unsigned int*)ws;                         // 2 MB
    __bf16*       Ht   = (__bf16*)(ws + (2ull << 20));              // 2 MB
    float*        Es   = (float*)(ws + (4ull << 20));               // 64 KB
    float*        Fs   = (float*)(ws + (4ull << 20) + (1 << 16));   // 64 KB
    float*        En   = (float*)(ws + (4ull << 20) + (2 << 16));   // 64 KB
    float*        Fn   = (float*)(ws + (4ull << 20) + (3 << 16));   // 64 KB
    float*        pden = (float*)(ws + (4ull << 20) + (4 << 16));   // <=512 KB
    float*        pacc = (float*)(ws + (5ull << 20));               // nsplit*4 MB

    int nsplit = 8;
    while (nsplit > 1 && ws_size < (5ull << 20) + (size_t)nsplit * (4ull << 20))
        nsplit >>= 1;
    const int ksplit = NN / nsplit;

    adjbits_kernel<<<NN, 256, 0, stream>>>(adj, adjw);
    prep_kernel<<<dim3(128, 4), 256, 0, stream>>>(feats, W, ak, Ht, Es, Fs, En, Fn);
    attn_kernel<<<dim3(128, 4, nsplit), 64, 0, stream>>>(adjw, Ht, Es, Fs, En, Fn, pacc, pden, ksplit);
    finalize_kernel<<<NN, 256, 0, stream>>>(pacc, pden, out, nsplit);
}

// Round 4
// 94.725 us; speedup vs baseline: 1.0129x; 1.0129x over previous
//
#include <hip/hip_runtime.h>
#include <math.h>

#define NN 4096
#define FF 128
#define DD 64
#define HH 4
#define NC 256  // HH*DD output columns

typedef __bf16 bf16x8 __attribute__((ext_vector_type(8)));
typedef float  f32x4  __attribute__((ext_vector_type(4)));

// ---------------------------------------------------------------------------
// Kernel 0: adjacency int32 -> bitmask. adjw[n*128 + w] bit b = (adj[n][w*32+b])
// ---------------------------------------------------------------------------
__global__ __launch_bounds__(256) void adjbits_kernel(
    const int* __restrict__ adj, unsigned int* __restrict__ adjw)
{
    const int row  = blockIdx.x;
    const int wv   = threadIdx.x >> 6;
    const int lane = threadIdx.x & 63;
    for (int c = wv; c < 64; c += 4) {
        int a = adj[(size_t)row * NN + c * 64 + lane];
        unsigned long long m = __ballot(a != 0);
        if (lane == 0) {
            adjw[row * 128 + c * 2]     = (unsigned int)m;
            adjw[row * 128 + c * 2 + 1] = (unsigned int)(m >> 32);
        }
    }
}

// ---------------------------------------------------------------------------
// Kernel 1: h = features @ W[h]; emit Ht (bf16 [h][d][m] via LDS transpose)
// and exp tables Es=exp(a_self), Fs=exp(.2 a_self), En=exp(a_neigh),
// Fn=exp(.2 a_neigh)  (fp32, [h][n]).
// ---------------------------------------------------------------------------
__global__ __launch_bounds__(256) void prep_kernel(
    const float* __restrict__ feats, const float* __restrict__ W,
    const float* __restrict__ ak, __bf16* __restrict__ Ht,
    float* __restrict__ Es, float* __restrict__ Fs,
    float* __restrict__ En, float* __restrict__ Fn)
{
    __shared__ float Wt[64 * 132];
    __shared__ float ft[32 * 128];
    __shared__ float hlds[32 * 65];
    const int t  = threadIdx.x;
    const int h  = blockIdx.y;
    const int n0 = blockIdx.x * 32;

    {
        const float* Wh = W + h * (FF * DD);
        #pragma unroll
        for (int j = 0; j < 8; ++j) {
            int idx = j * 256 + t;
            int f   = idx >> 4;
            int d4  = idx & 15;
            float4 v = ((const float4*)Wh)[idx];
            Wt[(d4 * 4 + 0) * 132 + f] = v.x;
            Wt[(d4 * 4 + 1) * 132 + f] = v.y;
            Wt[(d4 * 4 + 2) * 132 + f] = v.z;
            Wt[(d4 * 4 + 3) * 132 + f] = v.w;
        }
        #pragma unroll
        for (int j = 0; j < 4; ++j) {
            int idx = j * 256 + t;
            int r = idx >> 5, f4 = idx & 31;
            ((float4*)ft)[r * 32 + f4] = ((const float4*)feats)[(size_t)(n0 + r) * 32 + f4];
        }
    }
    __syncthreads();

    const int d   = t & 63;
    const int wid = t >> 6;
    float acc[8];
    #pragma unroll
    for (int j = 0; j < 8; ++j) acc[j] = 0.f;

    for (int f4 = 0; f4 < 32; ++f4) {
        const float4 w4 = *(const float4*)&Wt[d * 132 + f4 * 4];
        #pragma unroll
        for (int j = 0; j < 8; ++j) {
            const int r = wid + 4 * j;
            const float4 fv = *(const float4*)&ft[r * 128 + f4 * 4];
            acc[j] += fv.x * w4.x + fv.y * w4.y + fv.z * w4.z + fv.w * w4.w;
        }
    }

    const float aks = ak[h * 128 + d];
    const float akn = ak[h * 128 + 64 + d];
    #pragma unroll
    for (int j = 0; j < 8; ++j) {
        const int r = wid + 4 * j;
        const float hv = acc[j];
        hlds[r * 65 + d] = hv;
        float v1 = hv * aks;
        float v2 = hv * akn;
        #pragma unroll
        for (int m = 32; m >= 1; m >>= 1) {
            v1 += __shfl_xor(v1, m, 64);
            v2 += __shfl_xor(v2, m, 64);
        }
        if (d == 0) {
            Es[h * NN + n0 + r] = __expf(v1);
            Fs[h * NN + n0 + r] = __expf(0.2f * v1);
            En[h * NN + n0 + r] = __expf(v2);
            Fn[h * NN + n0 + r] = __expf(0.2f * v2);
        }
    }
    __syncthreads();

    const int d2 = t >> 2;
    const int mq = (t & 3) * 8;
    bf16x8 v;
    #pragma unroll
    for (int i = 0; i < 8; ++i) v[i] = (__bf16)hlds[(mq + i) * 65 + d2];
    *(bf16x8*)(Ht + (size_t)(h * 64 + d2) * NN + n0 + mq) = v;
}

// ---------------------------------------------------------------------------
// Kernel 2: MFMA attention, depth-2 software pipeline with NAMED stage regs.
// 1 wave/block; grid (128 row-tiles, 4 heads, nsplit). P = mask ?
// max(Es*En, Fs*Fn) : 0. Loads (B-frags + tables + mask) issued 2 chunks
// ahead of use -> issue-bound steady state.
// ---------------------------------------------------------------------------
__global__ __launch_bounds__(64, 3) void attn_kernel(
    const unsigned int* __restrict__ adjw, const __bf16* __restrict__ Ht,
    const float* __restrict__ Es, const float* __restrict__ Fs,
    const float* __restrict__ En, const float* __restrict__ Fn,
    float* __restrict__ pacc, float* __restrict__ pden, int ksplit)
{
    const int l  = threadIdx.x;
    const int lr = l & 15;
    const int kg = l >> 4;
    const int h  = blockIdx.y;
    const int n0 = blockIdx.x * 32;
    const int s  = blockIdx.z;

    const float es0 = Es[h * NN + n0 + lr];
    const float fs0 = Fs[h * NN + n0 + lr];
    const float es1 = Es[h * NN + n0 + 16 + lr];
    const float fs1 = Fs[h * NN + n0 + 16 + lr];
    const float* __restrict__ EnB = En + h * NN;
    const float* __restrict__ FnB = Fn + h * NN;
    const __bf16* __restrict__ htb = Ht + (size_t)(h * 64) * NN;
    const int row0 = n0 + lr, row1 = n0 + 16 + lr;

    f32x4 acc[2][4] = {};
    f32x4 dacc[2]   = {};
    bf16x8 ones;
    #pragma unroll
    for (int j = 0; j < 8; ++j) ones[j] = (__bf16)1.0f;

    const int nchunk = ksplit >> 5;     // 32 at nsplit=4 (even)
    const int mstart = s * ksplit;

    // ---- pipeline stage registers (named; no runtime indexing) ----
    float4 en0_0, en1_0, fn0_0, fn1_0;  unsigned int mk0_0, mk1_0;  bf16x8 B_0[4];
    float4 en0_1, en1_1, fn0_1, fn1_1;  unsigned int mk0_1, mk1_1;  bf16x8 B_1[4];
    bf16x8 a0_0, a1_0, a0_1, a1_1;

#define LOADP(S, CIDX) do {                                                   \
        int _c = (CIDX); _c = _c < nchunk ? _c : nchunk - 1;                  \
        const int _m0 = mstart + _c * 32;                                     \
        const int _mb = _m0 + kg * 8;                                         \
        en0_##S = *(const float4*)(EnB + _mb);                                \
        en1_##S = *(const float4*)(EnB + _mb + 4);                            \
        fn0_##S = *(const float4*)(FnB + _mb);                                \
        fn1_##S = *(const float4*)(FnB + _mb + 4);                            \
        mk0_##S = adjw[row0 * 128 + (_m0 >> 5)];                              \
        mk1_##S = adjw[row1 * 128 + (_m0 >> 5)];                              \
        _Pragma("unroll")                                                     \
        for (int cb = 0; cb < 4; ++cb)                                        \
            B_##S[cb] = *(const bf16x8*)(htb + (size_t)(cb * 16 + lr) * NN + _mb); \
    } while (0)

#define COMPA(S) do {                                                         \
        const float env[8] = {en0_##S.x, en0_##S.y, en0_##S.z, en0_##S.w,     \
                              en1_##S.x, en1_##S.y, en1_##S.z, en1_##S.w};    \
        const float fnv[8] = {fn0_##S.x, fn0_##S.y, fn0_##S.z, fn0_##S.w,     \
                              fn1_##S.x, fn1_##S.y, fn1_##S.z, fn1_##S.w};    \
        const unsigned int b0 = (mk0_##S >> (kg * 8)) & 0xffu;                \
        const unsigned int b1 = (mk1_##S >> (kg * 8)) & 0xffu;                \
        _Pragma("unroll")                                                     \
        for (int j = 0; j < 8; ++j) {                                         \
            float v0 = fmaxf(es0 * env[j], fs0 * fnv[j]);                     \
            float v1 = fmaxf(es1 * env[j], fs1 * fnv[j]);                     \
            v0 = ((b0 >> j) & 1u) ? v0 : 0.f;                                 \
            v1 = ((b1 >> j) & 1u) ? v1 : 0.f;                                 \
            a0_##S[j] = (__bf16)v0;                                           \
            a1_##S[j] = (__bf16)v1;                                           \
        }                                                                     \
    } while (0)

#define MFMAS(S) do {                                                         \
        __builtin_amdgcn_s_setprio(1);                                        \
        _Pragma("unroll")                                                     \
        for (int cb = 0; cb < 4; ++cb) {                                      \
            acc[0][cb] = __builtin_amdgcn_mfma_f32_16x16x32_bf16(a0_##S, B_##S[cb], acc[0][cb], 0, 0, 0); \
            acc[1][cb] = __builtin_amdgcn_mfma_f32_16x16x32_bf16(a1_##S, B_##S[cb], acc[1][cb], 0, 0, 0); \
        }                                                                     \
        dacc[0] = __builtin_amdgcn_mfma_f32_16x16x32_bf16(a0_##S, ones, dacc[0], 0, 0, 0); \
        dacc[1] = __builtin_amdgcn_mfma_f32_16x16x32_bf16(a1_##S, ones, dacc[1], 0, 0, 0); \
        __builtin_amdgcn_s_setprio(0);                                        \
    } while (0)

    LOADP(0, 0);
    LOADP(1, 1);
    COMPA(0);

    for (int c = 0; c < nchunk; c += 2) {
        MFMAS(0);
        LOADP(0, c + 2);
        COMPA(1);
        MFMAS(1);
        LOADP(1, c + 3);
        COMPA(0);          // A for chunk c+2 (clamped junk on last iter; unused)
    }
#undef LOADP
#undef COMPA
#undef MFMAS

    #pragma unroll
    for (int rb = 0; rb < 2; ++rb) {
        #pragma unroll
        for (int r = 0; r < 4; ++r) {
            const int row = n0 + rb * 16 + kg * 4 + r;
            #pragma unroll
            for (int cb = 0; cb < 4; ++cb)
                pacc[((size_t)(s * NN + row)) * NC + h * 64 + cb * 16 + lr] = acc[rb][cb][r];
            if (lr == 0)
                pden[(s * NN + row) * 4 + h] = dacc[rb][r];
        }
    }
}

// ---------------------------------------------------------------------------
// Kernel 3: reduce splits, normalize, ReLU.
// ---------------------------------------------------------------------------
__global__ __launch_bounds__(256) void finalize_kernel(
    const float* __restrict__ pacc, const float* __restrict__ pden,
    float* __restrict__ out, int nsplit)
{
    const int n = blockIdx.x;
    const int c = threadIdx.x;
    float a = 0.f, d = 0.f;
    for (int s = 0; s < nsplit; ++s) {
        a += pacc[((size_t)(s * NN + n)) * NC + c];
        d += pden[(s * NN + n) * 4 + (c >> 6)];
    }
    const float o = (d > 0.f) ? a / d : 0.f;
    out[(size_t)n * NC + c] = o > 0.f ? o : 0.f;
}

// ---------------------------------------------------------------------------
extern "C" void kernel_launch(void* const* d_in, const int* in_sizes, int n_in,
                              void* d_out, int out_size, void* d_ws, size_t ws_size,
                              hipStream_t stream)
{
    const int*   adj   = (const int*)d_in[0];
    const float* feats = (const float*)d_in[1];
    const float* W     = (const float*)d_in[2];
    const float* ak    = (const float*)d_in[3];
    float*       out   = (float*)d_out;

    char* ws = (char*)d_ws;
    unsigned int* adjw = (unsigned int*)ws;                         // 2 MB
    __bf16*       Ht   = (__bf16*)(ws + (2ull << 20));              // 2 MB
    float*        Es   = (float*)(ws + (4ull << 20));               // 64 KB
    float*        Fs   = (float*)(ws + (4ull << 20) + (1 << 16));   // 64 KB
    float*        En   = (float*)(ws + (4ull << 20) + (2 << 16));   // 64 KB
    float*        Fn   = (float*)(ws + (4ull << 20) + (3 << 16));   // 64 KB
    float*        pden = (float*)(ws + (4ull << 20) + (4 << 16));   // <=512 KB
    float*        pacc = (float*)(ws + (5ull << 20));               // nsplit*4 MB

    int nsplit = 4;
    while (nsplit > 1 && ws_size < (5ull << 20) + (size_t)nsplit * (4ull << 20))
        nsplit >>= 1;
    const int ksplit = NN / nsplit;

    adjbits_kernel<<<NN, 256, 0, stream>>>(adj, adjw);
    prep_kernel<<<dim3(128, 4), 256, 0, stream>>>(feats, W, ak, Ht, Es, Fs, En, Fn);
    attn_kernel<<<dim3(128, 4, nsplit), 64, 0, stream>>>(adjw, Ht, Es, Fs, En, Fn, pacc, pden, ksplit);
    finalize_kernel<<<NN, 256, 0, stream>>>(pacc, pden, out, nsplit);
}

// Round 5
// 67.344 us; speedup vs baseline: 1.4247x; 1.4066x over previous
//
#include <hip/hip_runtime.h>
#include <math.h>

#define NN 4096
#define FF 128
#define DD 64
#define HH 4
#define NC 256  // HH*DD output columns

typedef _Float16 f16x8 __attribute__((ext_vector_type(8)));
typedef _Float16 f16x2 __attribute__((ext_vector_type(2)));
typedef float    f32x4 __attribute__((ext_vector_type(4)));

// ---------------------------------------------------------------------------
// Kernel 0: adjacency int32 -> bitmask. adjw[n*128 + w] bit b = (adj[n][w*32+b])
// ---------------------------------------------------------------------------
__global__ __launch_bounds__(256) void adjbits_kernel(
    const int* __restrict__ adj, unsigned int* __restrict__ adjw)
{
    const int row  = blockIdx.x;
    const int wv   = threadIdx.x >> 6;
    const int lane = threadIdx.x & 63;
    for (int c = wv; c < 64; c += 4) {
        int a = adj[(size_t)row * NN + c * 64 + lane];
        unsigned long long m = __ballot(a != 0);
        if (lane == 0) {
            adjw[row * 128 + c * 2]     = (unsigned int)m;
            adjw[row * 128 + c * 2 + 1] = (unsigned int)(m >> 32);
        }
    }
}

// ---------------------------------------------------------------------------
// Kernel 1: h = features @ W[h]; emit Ht (f16 [h][d][m] via LDS transpose)
// and f16 exp tables Es=exp(a_self), Fs=exp(.2 a_self), En=exp(a_neigh),
// Fn=exp(.2 a_neigh), each [h][n].
// ---------------------------------------------------------------------------
__global__ __launch_bounds__(256) void prep_kernel(
    const float* __restrict__ feats, const float* __restrict__ W,
    const float* __restrict__ ak, _Float16* __restrict__ Ht,
    _Float16* __restrict__ Es, _Float16* __restrict__ Fs,
    _Float16* __restrict__ En, _Float16* __restrict__ Fn)
{
    __shared__ float Wt[64 * 132];
    __shared__ float ft[32 * 128];
    __shared__ float hlds[32 * 65];
    const int t  = threadIdx.x;
    const int h  = blockIdx.y;
    const int n0 = blockIdx.x * 32;

    {
        const float* Wh = W + h * (FF * DD);
        #pragma unroll
        for (int j = 0; j < 8; ++j) {
            int idx = j * 256 + t;
            int f   = idx >> 4;
            int d4  = idx & 15;
            float4 v = ((const float4*)Wh)[idx];
            Wt[(d4 * 4 + 0) * 132 + f] = v.x;
            Wt[(d4 * 4 + 1) * 132 + f] = v.y;
            Wt[(d4 * 4 + 2) * 132 + f] = v.z;
            Wt[(d4 * 4 + 3) * 132 + f] = v.w;
        }
        #pragma unroll
        for (int j = 0; j < 4; ++j) {
            int idx = j * 256 + t;
            int r = idx >> 5, f4 = idx & 31;
            ((float4*)ft)[r * 32 + f4] = ((const float4*)feats)[(size_t)(n0 + r) * 32 + f4];
        }
    }
    __syncthreads();

    const int d   = t & 63;
    const int wid = t >> 6;
    float acc[8];
    #pragma unroll
    for (int j = 0; j < 8; ++j) acc[j] = 0.f;

    for (int f4 = 0; f4 < 32; ++f4) {
        const float4 w4 = *(const float4*)&Wt[d * 132 + f4 * 4];
        #pragma unroll
        for (int j = 0; j < 8; ++j) {
            const int r = wid + 4 * j;
            const float4 fv = *(const float4*)&ft[r * 128 + f4 * 4];
            acc[j] += fv.x * w4.x + fv.y * w4.y + fv.z * w4.z + fv.w * w4.w;
        }
    }

    const float aks = ak[h * 128 + d];
    const float akn = ak[h * 128 + 64 + d];
    #pragma unroll
    for (int j = 0; j < 8; ++j) {
        const int r = wid + 4 * j;
        const float hv = acc[j];
        hlds[r * 65 + d] = hv;
        float v1 = hv * aks;
        float v2 = hv * akn;
        #pragma unroll
        for (int m = 32; m >= 1; m >>= 1) {
            v1 += __shfl_xor(v1, m, 64);
            v2 += __shfl_xor(v2, m, 64);
        }
        if (d == 0) {
            Es[h * NN + n0 + r] = (_Float16)__expf(v1);
            Fs[h * NN + n0 + r] = (_Float16)__expf(0.2f * v1);
            En[h * NN + n0 + r] = (_Float16)__expf(v2);
            Fn[h * NN + n0 + r] = (_Float16)__expf(0.2f * v2);
        }
    }
    __syncthreads();

    const int d2 = t >> 2;
    const int mq = (t & 3) * 8;
    f16x8 v;
    #pragma unroll
    for (int i = 0; i < 8; ++i) v[i] = (_Float16)hlds[(mq + i) * 65 + d2];
    *(f16x8*)(Ht + (size_t)(h * 64 + d2) * NN + n0 + mq) = v;
}

// ---------------------------------------------------------------------------
// Kernel 2: MFMA attention. Block = 4 waves, one head, 128 rows (wave w owns
// rows n0+32w..+32), m-split s (512 m = 16 chunks of 32). B-chunk (Ht 64x32)
// staged in LDS once per block (XOR slot-swizzle, involution on write+read);
// A = mask ? max(Es*En, Fs*Fn) : 0 computed with packed f16 ALU.
// mfma_f32_16x16x32_f16; A and B share the (kg,slot)->k map so any lane-k
// permutation cancels; C layout col=lane&15, row=(lane>>4)*4+reg [verified].
// ---------------------------------------------------------------------------
__global__ __launch_bounds__(256, 4) void attn_kernel(
    const unsigned int* __restrict__ adjw, const _Float16* __restrict__ Ht,
    const _Float16* __restrict__ Es, const _Float16* __restrict__ Fs,
    const _Float16* __restrict__ En, const _Float16* __restrict__ Fn,
    float* __restrict__ pacc, float* __restrict__ pden, int ksplit)
{
    __shared__ _Float16 Blds[2 * 64 * 32];   // 2 x 4KB double buffer

    const int t  = threadIdx.x;
    const int w  = t >> 6;
    const int l  = t & 63;
    const int lr = l & 15;
    const int kg = l >> 4;
    const int h  = blockIdx.y;
    const int s  = blockIdx.z;
    const int n0 = blockIdx.x * 128 + w * 32;
    const int mstart = s * ksplit;
    const int nchunk = ksplit >> 5;

    // stage addressing: thread t stages 16B for d-row sd, m-group sg (swizzled)
    const int sd = t >> 2;
    const int sg = (t & 3) ^ (sd & 3);
    const _Float16* __restrict__ hstage = Ht + (size_t)(h * 64 + sd) * NN + sg * 8;
    const int swoff = sd * 32 + (t & 3) * 8;          // LDS f16 offset for stage write
    const int slot8 = (kg ^ (lr & 3)) * 8;            // read-side swizzled slot

    // per-row scale pairs
    const _Float16 es0 = Es[h * NN + n0 + lr],      fs0 = Fs[h * NN + n0 + lr];
    const _Float16 es1 = Es[h * NN + n0 + 16 + lr], fs1 = Fs[h * NN + n0 + 16 + lr];
    const f16x2 es20 = {es0, es0}, fs20 = {fs0, fs0};
    const f16x2 es21 = {es1, es1}, fs21 = {fs1, fs1};

    const _Float16* __restrict__ EnB = En + (size_t)h * NN;
    const _Float16* __restrict__ FnB = Fn + (size_t)h * NN;
    const int row0 = n0 + lr, row1 = n0 + 16 + lr;
    const int wb   = mstart >> 5;                     // mask word base

    f32x4 acc[2][4] = {};
    f32x4 dacc[2]   = {};
    f16x8 ones;
    #pragma unroll
    for (int j = 0; j < 8; ++j) ones[j] = (_Float16)1.0f;

    union U8 { f16x8 v; unsigned int u[4]; };

    uint4 sreg = *(const uint4*)(hstage + mstart);    // stage regs for chunk 0

    for (int cq = 0; cq < (nchunk >> 2); ++cq) {
        // masks for 4 chunks (128 m) per row
        const uint4 mk0 = *(const uint4*)&adjw[(size_t)row0 * 128 + wb + cq * 4];
        const uint4 mk1 = *(const uint4*)&adjw[(size_t)row1 * 128 + wb + cq * 4];

        #pragma unroll
        for (int ci = 0; ci < 4; ++ci) {
            const int c  = cq * 4 + ci;
            const int m0 = mstart + c * 32;
            const int buf = (ci & 1) * 2048;

            // ---- write stage for chunk c, then make visible ----
            *(uint4*)&Blds[buf + swoff] = sreg;
            __syncthreads();

            // ---- prefetch stage for chunk c+1 (clamped on last) ----
            {
                const int mn = (c + 1 < nchunk) ? m0 + 32 : m0;
                sreg = *(const uint4*)(hstage + mn);
            }

            // ---- tables (broadcast 16B loads) ----
            const uint4 enq = *(const uint4*)(EnB + m0 + kg * 8);
            const uint4 fnq = *(const uint4*)(FnB + m0 + kg * 8);
            const unsigned int b0 =
                (ci == 0 ? mk0.x : ci == 1 ? mk0.y : ci == 2 ? mk0.z : mk0.w) >> (kg * 8);
            const unsigned int b1 =
                (ci == 0 ? mk1.x : ci == 1 ? mk1.y : ci == 2 ? mk1.z : mk1.w) >> (kg * 8);

            // ---- A-frags: packed f16 ----
            U8 A0, A1;
            #pragma unroll
            for (int p = 0; p < 4; ++p) {
                const unsigned int eu = p == 0 ? enq.x : p == 1 ? enq.y : p == 2 ? enq.z : enq.w;
                const unsigned int fu = p == 0 ? fnq.x : p == 1 ? fnq.y : p == 2 ? fnq.z : fnq.w;
                const f16x2 en2 = __builtin_bit_cast(f16x2, eu);
                const f16x2 fn2 = __builtin_bit_cast(f16x2, fu);
                const f16x2 v0 = __builtin_elementwise_max(es20 * en2, fs20 * fn2);
                const f16x2 v1 = __builtin_elementwise_max(es21 * en2, fs21 * fn2);
                const unsigned int mm0 = (((b0 >> (2 * p)) & 1u) ? 0x0000FFFFu : 0u)
                                       | (((b0 >> (2 * p + 1)) & 1u) ? 0xFFFF0000u : 0u);
                const unsigned int mm1 = (((b1 >> (2 * p)) & 1u) ? 0x0000FFFFu : 0u)
                                       | (((b1 >> (2 * p + 1)) & 1u) ? 0xFFFF0000u : 0u);
                A0.u[p] = __builtin_bit_cast(unsigned int, v0) & mm0;
                A1.u[p] = __builtin_bit_cast(unsigned int, v1) & mm1;
            }

            // ---- B-frags from LDS (swizzled) + MFMA ----
            #pragma unroll
            for (int cb = 0; cb < 4; ++cb) {
                const f16x8 Bf = *(const f16x8*)&Blds[buf + (cb * 16 + lr) * 32 + slot8];
                acc[0][cb] = __builtin_amdgcn_mfma_f32_16x16x32_f16(A0.v, Bf, acc[0][cb], 0, 0, 0);
                acc[1][cb] = __builtin_amdgcn_mfma_f32_16x16x32_f16(A1.v, Bf, acc[1][cb], 0, 0, 0);
            }
            dacc[0] = __builtin_amdgcn_mfma_f32_16x16x32_f16(A0.v, ones, dacc[0], 0, 0, 0);
            dacc[1] = __builtin_amdgcn_mfma_f32_16x16x32_f16(A1.v, ones, dacc[1], 0, 0, 0);

            __syncthreads();   // all waves done with buf before it is rewritten
        }
    }

    #pragma unroll
    for (int rb = 0; rb < 2; ++rb) {
        #pragma unroll
        for (int r = 0; r < 4; ++r) {
            const int row = n0 + rb * 16 + kg * 4 + r;
            #pragma unroll
            for (int cb = 0; cb < 4; ++cb)
                pacc[((size_t)(s * NN + row)) * NC + h * 64 + cb * 16 + lr] = acc[rb][cb][r];
            if (lr == 0)
                pden[(s * NN + row) * 4 + h] = dacc[rb][r];
        }
    }
}

// ---------------------------------------------------------------------------
// Kernel 3: reduce splits, normalize, ReLU.
// ---------------------------------------------------------------------------
__global__ __launch_bounds__(256) void finalize_kernel(
    const float* __restrict__ pacc, const float* __restrict__ pden,
    float* __restrict__ out, int nsplit)
{
    const int n = blockIdx.x;
    const int c = threadIdx.x;
    float a = 0.f, d = 0.f;
    for (int s = 0; s < nsplit; ++s) {
        a += pacc[((size_t)(s * NN + n)) * NC + c];
        d += pden[(s * NN + n) * 4 + (c >> 6)];
    }
    const float o = (d > 0.f) ? a / d : 0.f;
    out[(size_t)n * NC + c] = o > 0.f ? o : 0.f;
}

// ---------------------------------------------------------------------------
extern "C" void kernel_launch(void* const* d_in, const int* in_sizes, int n_in,
                              void* d_out, int out_size, void* d_ws, size_t ws_size,
                              hipStream_t stream)
{
    const int*   adj   = (const int*)d_in[0];
    const float* feats = (const float*)d_in[1];
    const float* W     = (const float*)d_in[2];
    const float* ak    = (const float*)d_in[3];
    float*       out   = (float*)d_out;

    char* ws = (char*)d_ws;
    unsigned int* adjw = (unsigned int*)ws;                          // 2 MB
    _Float16*     Ht   = (_Float16*)(ws + (2ull << 20));             // 2 MB
    _Float16*     Es   = (_Float16*)(ws + (4ull << 20));             // 32 KB
    _Float16*     Fs   = (_Float16*)(ws + (4ull << 20) + (1 << 16)); // 32 KB
    _Float16*     En   = (_Float16*)(ws + (4ull << 20) + (2 << 16)); // 32 KB
    _Float16*     Fn   = (_Float16*)(ws + (4ull << 20) + (3 << 16)); // 32 KB
    float*        pden = (float*)(ws + (4ull << 20) + (4 << 16));    // <=512 KB
    float*        pacc = (float*)(ws + (5ull << 20));                // nsplit*4 MB

    int nsplit = 8;
    while (nsplit > 1 && ws_size < (5ull << 20) + (size_t)nsplit * (4ull << 20))
        nsplit >>= 1;
    const int ksplit = NN / nsplit;

    adjbits_kernel<<<NN, 256, 0, stream>>>(adj, adjw);
    prep_kernel<<<dim3(128, 4), 256, 0, stream>>>(feats, W, ak, Ht, Es, Fs, En, Fn);
    attn_kernel<<<dim3(32, 4, nsplit), 256, 0, stream>>>(adjw, Ht, Es, Fs, En, Fn, pacc, pden, ksplit);
    finalize_kernel<<<NN, 256, 0, stream>>>(pacc, pden, out, nsplit);
}